// Round 1
// baseline (967.712 us; speedup 1.0000x reference)
//
#include <hip/hip_runtime.h>

#define N_NODES 50000
#define N_EDGES 800000
#define E_TOT (N_EDGES + N_NODES)
#define D 128
#define N_GRAPHS 64
#define NEG_SLOPE 0.2f

__device__ __forceinline__ float wave_max(float v) {
  #pragma unroll
  for (int off = 32; off > 0; off >>= 1) v = fmaxf(v, __shfl_xor(v, off));
  return v;
}
__device__ __forceinline__ float wave_sum(float v) {
  #pragma unroll
  for (int off = 32; off > 0; off >>= 1) v += __shfl_xor(v, off);
  return v;
}

// ---------------- CSR build ----------------
__global__ void k_count(const int* __restrict__ ei, int* __restrict__ cnt) {
  int e = blockIdx.x * blockDim.x + threadIdx.x;
  if (e >= E_TOT) return;
  int dst = (e < N_EDGES) ? ei[N_EDGES + e] : (e - N_EDGES);
  atomicAdd(&cnt[dst], 1);
}

__global__ __launch_bounds__(1024) void k_scan(const int* __restrict__ cnt,
                                               int* __restrict__ rowptr) {
  __shared__ int sm[1024];
  int running = 0;
  if (threadIdx.x == 0) rowptr[0] = 0;
  for (int base = 0; base < N_NODES; base += 1024) {
    int i = base + threadIdx.x;
    int v = (i < N_NODES) ? cnt[i] : 0;
    sm[threadIdx.x] = v;
    __syncthreads();
    #pragma unroll
    for (int off = 1; off < 1024; off <<= 1) {
      int t = (threadIdx.x >= off) ? sm[threadIdx.x - off] : 0;
      __syncthreads();
      sm[threadIdx.x] += t;
      __syncthreads();
    }
    int incl = sm[threadIdx.x];
    if (i < N_NODES) rowptr[i + 1] = running + incl;
    running += sm[1023];
    __syncthreads();
  }
}

__global__ void k_fill(const int* __restrict__ ei, const int* __restrict__ rowptr,
                       int* __restrict__ fill, int* __restrict__ col) {
  int e = blockIdx.x * blockDim.x + threadIdx.x;
  if (e >= E_TOT) return;
  int src, dst;
  if (e < N_EDGES) { src = ei[e]; dst = ei[N_EDGES + e]; }
  else { src = e - N_EDGES; dst = src; }
  int pos = rowptr[dst] + atomicAdd(&fill[dst], 1);
  col[pos] = src;
}

// ---------------- GEMM: H = X @ W (fp32, 64x128 tile) ----------------
__global__ __launch_bounds__(256) void k_gemm(const float* __restrict__ X,
                                              const float* __restrict__ W,
                                              float* __restrict__ H) {
  __shared__ float Xs[32][64];   // [k][m] transposed
  __shared__ float Ws[32][128];  // [k][n]
  const int tid = threadIdx.x;
  const int cg = tid & 15;   // 16 col groups of 8
  const int rg = tid >> 4;   // 16 row groups of 4
  const int rowbase = blockIdx.x * 64;
  const int r0 = rg * 4;
  const int c0 = cg * 8;
  float acc[4][8];
  #pragma unroll
  for (int i = 0; i < 4; i++)
    #pragma unroll
    for (int j = 0; j < 8; j++) acc[i][j] = 0.f;

  for (int kt = 0; kt < 4; ++kt) {
    #pragma unroll
    for (int i = 0; i < 2; i++) {
      int e = tid + i * 256;           // 0..511 float4s of X tile
      int row = e >> 3, kq = e & 7;
      int grow = rowbase + row;
      float4 f = make_float4(0.f, 0.f, 0.f, 0.f);
      if (grow < N_NODES)
        f = *reinterpret_cast<const float4*>(&X[(size_t)grow * D + kt * 32 + kq * 4]);
      Xs[kq * 4 + 0][row] = f.x;
      Xs[kq * 4 + 1][row] = f.y;
      Xs[kq * 4 + 2][row] = f.z;
      Xs[kq * 4 + 3][row] = f.w;
    }
    #pragma unroll
    for (int i = 0; i < 4; i++) {
      int e = tid + i * 256;           // 0..1023 float4s of W tile
      int kr = e >> 5, cq = e & 31;
      *reinterpret_cast<float4*>(&Ws[kr][cq * 4]) =
          *reinterpret_cast<const float4*>(&W[(size_t)(kt * 32 + kr) * D + cq * 4]);
    }
    __syncthreads();
    #pragma unroll
    for (int k = 0; k < 32; k++) {
      float4 a = *reinterpret_cast<const float4*>(&Xs[k][r0]);
      float4 b0 = *reinterpret_cast<const float4*>(&Ws[k][c0]);
      float4 b1 = *reinterpret_cast<const float4*>(&Ws[k][c0 + 4]);
      float av[4] = {a.x, a.y, a.z, a.w};
      float bv[8] = {b0.x, b0.y, b0.z, b0.w, b1.x, b1.y, b1.z, b1.w};
      #pragma unroll
      for (int i = 0; i < 4; i++)
        #pragma unroll
        for (int j = 0; j < 8; j++)
          acc[i][j] = fmaf(av[i], bv[j], acc[i][j]);
    }
    __syncthreads();
  }
  #pragma unroll
  for (int i = 0; i < 4; i++) {
    int grow = rowbase + r0 + i;
    if (grow < N_NODES) {
      *reinterpret_cast<float4*>(&H[(size_t)grow * D + c0]) =
          make_float4(acc[i][0], acc[i][1], acc[i][2], acc[i][3]);
      *reinterpret_cast<float4*>(&H[(size_t)grow * D + c0 + 4]) =
          make_float4(acc[i][4], acc[i][5], acc[i][6], acc[i][7]);
    }
  }
}

// ---------------- per-node attention dots ----------------
__global__ __launch_bounds__(256) void k_alpha(const float* __restrict__ H,
                                               const float* __restrict__ asrc,
                                               const float* __restrict__ adst,
                                               float* __restrict__ alpha_s,
                                               float* __restrict__ alpha_d) {
  int wid = threadIdx.x >> 6;
  int lane = threadIdx.x & 63;
  int node = blockIdx.x * 4 + wid;
  if (node >= N_NODES) return;
  float2 h = *reinterpret_cast<const float2*>(&H[(size_t)node * D + lane * 2]);
  float2 as = *reinterpret_cast<const float2*>(&asrc[lane * 2]);
  float2 ad = *reinterpret_cast<const float2*>(&adst[lane * 2]);
  float s = h.x * as.x + h.y * as.y;
  float d = h.x * ad.x + h.y * ad.y;
  s = wave_sum(s);
  d = wave_sum(d);
  if (lane == 0) {
    alpha_s[node] = s;
    alpha_d[node] = d;
  }
}

// ---------------- fused segment softmax + aggregate + bias + relu ----------------
__global__ __launch_bounds__(256) void k_agg(const float* __restrict__ H,
                                             const int* __restrict__ rowptr,
                                             const int* __restrict__ col,
                                             const float* __restrict__ alpha_s,
                                             const float* __restrict__ alpha_d,
                                             const float* __restrict__ bias,
                                             float* __restrict__ Out) {
  int wid = threadIdx.x >> 6;
  int lane = threadIdx.x & 63;
  int node = blockIdx.x * 4 + wid;
  if (node >= N_NODES) return;
  int start = rowptr[node], end = rowptr[node + 1];
  float ad = alpha_d[node];

  float m = -1e30f;
  for (int base = start; base < end; base += 64) {
    int j = base + lane;
    if (j < end) {
      float e = alpha_s[col[j]] + ad;
      e = e >= 0.f ? e : NEG_SLOPE * e;
      m = fmaxf(m, e);
    }
  }
  m = wave_max(m);

  float dsum = 0.f;
  for (int base = start; base < end; base += 64) {
    int j = base + lane;
    if (j < end) {
      float e = alpha_s[col[j]] + ad;
      e = e >= 0.f ? e : NEG_SLOPE * e;
      dsum += expf(e - m);
    }
  }
  dsum = wave_sum(dsum);
  float inv = 1.f / (dsum + 1e-16f);

  float2 acc = make_float2(0.f, 0.f);
  for (int j = start; j < end; ++j) {
    int s = col[j];
    float e = alpha_s[s] + ad;
    e = e >= 0.f ? e : NEG_SLOPE * e;
    float w = expf(e - m);
    float2 hv = *reinterpret_cast<const float2*>(&H[(size_t)s * D + lane * 2]);
    acc.x = fmaf(w, hv.x, acc.x);
    acc.y = fmaf(w, hv.y, acc.y);
  }
  float2 bv = *reinterpret_cast<const float2*>(&bias[lane * 2]);
  float ox = fmaxf(acc.x * inv + bv.x, 0.f);
  float oy = fmaxf(acc.y * inv + bv.y, 0.f);
  *reinterpret_cast<float2*>(&Out[(size_t)node * D + lane * 2]) = make_float2(ox, oy);
}

// ---------------- pool + fc ----------------
__global__ __launch_bounds__(128) void k_pool(const float* __restrict__ H,
                                              const int* __restrict__ batch,
                                              const float* __restrict__ fcW,
                                              const float* __restrict__ fcb,
                                              float* __restrict__ out) {
  __shared__ float sm[128];
  int b = blockIdx.x;
  int c = threadIdx.x;
  int lo = 0, hi = N_NODES;
  while (lo < hi) { int mid = (lo + hi) >> 1; if (batch[mid] < b) lo = mid + 1; else hi = mid; }
  int s0 = lo;
  lo = 0; hi = N_NODES;
  while (lo < hi) { int mid = (lo + hi) >> 1; if (batch[mid] < b + 1) lo = mid + 1; else hi = mid; }
  int s1 = lo;
  float sum = 0.f;
  for (int n = s0; n < s1; ++n) sum += H[(size_t)n * D + c];
  float cntf = (float)(s1 - s0);
  float pooled = sum / fmaxf(cntf, 1.f);
  sm[c] = pooled * fcW[c];
  __syncthreads();
  #pragma unroll
  for (int off = 64; off > 0; off >>= 1) {
    if (c < off) sm[c] += sm[c + off];
    __syncthreads();
  }
  if (c == 0) out[b] = sm[0] + fcb[0];
}

extern "C" void kernel_launch(void* const* d_in, const int* in_sizes, int n_in,
                              void* d_out, int out_size, void* d_ws, size_t ws_size,
                              hipStream_t stream) {
  const float* x = (const float*)d_in[0];
  const int* ei = (const int*)d_in[1];
  const int* batch = (const int*)d_in[2];
  const float* W[4]   = {(const float*)d_in[3], (const float*)d_in[7],
                         (const float*)d_in[11], (const float*)d_in[15]};
  const float* asr[4] = {(const float*)d_in[4], (const float*)d_in[8],
                         (const float*)d_in[12], (const float*)d_in[16]};
  const float* adt[4] = {(const float*)d_in[5], (const float*)d_in[9],
                         (const float*)d_in[13], (const float*)d_in[17]};
  const float* bs[4]  = {(const float*)d_in[6], (const float*)d_in[10],
                         (const float*)d_in[14], (const float*)d_in[18]};
  const float* fcW = (const float*)d_in[19];
  const float* fcb = (const float*)d_in[20];
  float* out = (float*)d_out;

  char* ws = (char*)d_ws;
  size_t off = 0;
  float* hA = (float*)(ws + off); off += (size_t)N_NODES * D * 4;     // gemm out
  float* hB = (float*)(ws + off); off += (size_t)N_NODES * D * 4;     // layer out
  float* alpha_s = (float*)(ws + off); off += (size_t)N_NODES * 4;
  float* alpha_d = (float*)(ws + off); off += (size_t)N_NODES * 4;
  int* cnt  = (int*)(ws + off); off += (size_t)N_NODES * 4;
  int* fill = (int*)(ws + off); off += (size_t)N_NODES * 4;           // contiguous after cnt
  int* rowptr = (int*)(ws + off); off += (size_t)(N_NODES + 1) * 4 + 12;
  int* col = (int*)(ws + off); off += (size_t)E_TOT * 4;
  (void)ws_size; (void)in_sizes; (void)n_in; (void)out_size;

  hipMemsetAsync(cnt, 0, (size_t)N_NODES * 4 * 2, stream);  // zero cnt + fill
  int eb = (E_TOT + 255) / 256;
  k_count<<<eb, 256, 0, stream>>>(ei, cnt);
  k_scan<<<1, 1024, 0, stream>>>(cnt, rowptr);
  k_fill<<<eb, 256, 0, stream>>>(ei, rowptr, fill, col);

  const float* in = x;
  for (int l = 0; l < 4; ++l) {
    k_gemm<<<(N_NODES + 63) / 64, 256, 0, stream>>>(in, W[l], hA);
    k_alpha<<<(N_NODES + 3) / 4, 256, 0, stream>>>(hA, asr[l], adt[l], alpha_s, alpha_d);
    k_agg<<<(N_NODES + 3) / 4, 256, 0, stream>>>(hA, rowptr, col, alpha_s, alpha_d, bs[l], hB);
    in = hB;
  }
  k_pool<<<N_GRAPHS, 128, 0, stream>>>(hB, batch, fcW, fcb, out);
}